// Round 1
// baseline (313.406 us; speedup 1.0000x reference)
//
#include <hip/hip_runtime.h>
#include <math.h>

#define NP 32      // number of planes
#define KC 31      // kernel cap (max taps)
#define HH 512
#define WW 512
#define BB 4
#define CC 3

#define TXO 32     // output tile x
#define TYO 32     // output tile y
#define RPX 4      // outputs per thread (x)
#define TCOLS 64   // LDS tile cols  = 32 outputs + 16 left + 16 right halo/align
#define TROWS 62   // LDS tile rows  = 32 outputs + 15+15 halo
#define WSTR 33    // weight LDS row stride (bank-conflict-free)

// Per-plane padded 1D Gaussian rows, rebuilt every launch (graph-safe).
__device__ float g_wtab[NP * 32];

__global__ void init_wtab_kernel() {
    int p = threadIdx.x;
    if (p >= NP) return;
    const double stepd = 50.0 / 31.0;
    double coc = (p < 31) ? (double)p * stepd : 50.0;   // numpy linspace semantics
    float row[KC];
    #pragma unroll
    for (int i = 0; i < KC; ++i) row[i] = 0.f;
    if (coc < 0.5) {
        row[KC / 2] = 1.f;  // identity plane
    } else {
        double sigma = coc / 2.355;
        int k = (int)(2.0 * coc + 1.0);   // trunc, matches python int()
        if ((k & 1) == 0) k += 1;
        if (k > KC) k = KC;
        int h = k / 2;
        float denom = (float)(2.0 * sigma * sigma);
        float tmp[KC];
        float s = 0.f;
        for (int t = 0; t < k; ++t) {
            float cd = (float)(t - h);
            float v = expf(-(cd * cd) / denom);
            tmp[t] = v;
            s += v;
        }
        for (int t = 0; t < k; ++t) row[(KC / 2) - h + t] = tmp[t] / s;
    }
    for (int i = 0; i < 32; ++i) g_wtab[p * 32 + i] = (i < KC) ? row[i] : 0.f;
}

__device__ __forceinline__ double plane_of(int i) {
    const double stepd = 50.0 / 31.0;
    return (i < 31) ? (double)i * stepd : 50.0;
}

__launch_bounds__(256, 2)
__global__ void defocus_kernel(const float* __restrict__ img,
                               const float* __restrict__ coc,
                               float* __restrict__ out) {
    const int tx = threadIdx.x;            // 0..7
    const int ty = threadIdx.y;            // 0..31
    const int tid = ty * 8 + tx;
    const int tilex = blockIdx.x * TXO;
    const int tiley = blockIdx.y * TYO;
    const int b = blockIdx.z;

    __shared__ __align__(16) float wlds[NP * WSTR];
    __shared__ __align__(16) float tile[TROWS * TCOLS];

    // stage weight table into LDS (stride 33 -> conflict-free row gathers)
    for (int f = tid; f < NP * KC; f += 256) {
        int p = f / KC;
        int d = f - p * KC;
        wlds[p * WSTR + d] = g_wtab[p * 32 + d];
    }

    const int yo = tiley + ty;
    const int xo = tilex + tx * RPX;

    // --- per-pixel bin index, exact double-precision boundary semantics ---
    const float4 cv = *(const float4*)&coc[((size_t)b * HH + yo) * WW + xo];
    const float cocf[RPX] = {cv.x, cv.y, cv.z, cv.w};
    int idx[RPX];
    #pragma unroll
    for (int j = 0; j < RPX; ++j) {
        const double stepd = 50.0 / 31.0;
        double cd = (double)cocf[j];
        int i0 = (int)floor(cd / stepd + 0.5);
        i0 = min(max(i0, 0), 31);
        if (i0 > 0 && cd <= 0.5 * (plane_of(i0 - 1) + plane_of(i0))) {
            i0 -= 1;
        } else if (i0 < 31 && cd > 0.5 * (plane_of(i0) + plane_of(i0 + 1))) {
            i0 += 1;
        }
        idx[j] = i0;
    }

    __syncthreads();  // wlds ready

    // weight rows -> registers (4 x 31 VGPRs)
    float wr[RPX][KC];
    #pragma unroll
    for (int j = 0; j < RPX; ++j) {
        #pragma unroll
        for (int d = 0; d < KC; ++d) wr[j][d] = wlds[idx[j] * WSTR + d];
    }

    for (int c = 0; c < CC; ++c) {
        __syncthreads();  // protect tile from previous iteration's readers
        const float* src = img + (size_t)(b * CC + c) * HH * WW;
        for (int f = tid; f < TROWS * TCOLS; f += 256) {
            int r = f >> 6;        // /64
            int cc2 = f & 63;
            int gy = tiley - 15 + r;
            int gx = tilex - 16 + cc2;
            float v = 0.f;
            if ((unsigned)gy < (unsigned)HH && (unsigned)gx < (unsigned)WW)
                v = src[gy * WW + gx];
            tile[f] = v;
        }
        __syncthreads();

        float acc[RPX] = {0.f, 0.f, 0.f, 0.f};
        for (int dy = 0; dy < KC; ++dy) {
            float rs[RPX] = {0.f, 0.f, 0.f, 0.f};
            const float* rowp = &tile[(ty + dy) * TCOLS + tx * RPX];
            #pragma unroll
            for (int mq = 0; mq < 9; ++mq) {
                const float4 v4 = *(const float4*)(rowp + mq * 4);
                const float vv[4] = {v4.x, v4.y, v4.z, v4.w};
                #pragma unroll
                for (int q = 0; q < 4; ++q) {
                    const int m = mq * 4 + q;
                    #pragma unroll
                    for (int j = 0; j < RPX; ++j) {
                        const int dx = m - j - 1;   // col offset into 31-tap row
                        if (dx >= 0 && dx < KC) rs[j] += wr[j][dx] * vv[q];
                    }
                }
            }
            #pragma unroll
            for (int j = 0; j < RPX; ++j)
                acc[j] += wlds[idx[j] * WSTR + dy] * rs[j];
        }

        *(float4*)&out[((size_t)(b * CC + c) * HH + yo) * WW + xo] =
            make_float4(acc[0], acc[1], acc[2], acc[3]);
    }
}

extern "C" void kernel_launch(void* const* d_in, const int* in_sizes, int n_in,
                              void* d_out, int out_size, void* d_ws, size_t ws_size,
                              hipStream_t stream) {
    const float* sharp = (const float*)d_in[0];
    const float* cocm  = (const float*)d_in[1];
    float* out = (float*)d_out;

    init_wtab_kernel<<<1, 64, 0, stream>>>();
    dim3 grid(WW / TXO, HH / TYO, BB);
    dim3 block(8, 32, 1);
    defocus_kernel<<<grid, block, 0, stream>>>(sharp, cocm, out);
}

// Round 2
// 308.751 us; speedup vs baseline: 1.0151x; 1.0151x over previous
//
#include <hip/hip_runtime.h>
#include <math.h>

typedef _Float16 h2_t __attribute__((ext_vector_type(2)));
typedef _Float16 h4_t __attribute__((ext_vector_type(4)));
typedef _Float16 h8_t __attribute__((ext_vector_type(8)));

#define NP 32
#define KC 31
#define HH 512
#define WW 512
#define BB 4
#define CC 3

#define TXO 32
#define TYO 32
#define TROWS 62      // 32 outputs + 15 + 15 halo
#define TWORDS 48     // half2-words per tile row (96 halves, 62 used, stride%32==16)
#define WSTR 36       // weight table plane stride in half2-words (%32 != 0 -> gather spreads banks)

// Packed per-plane 1D Gaussian taps, phase A = (g[2m],g[2m+1]), phase B = (g[2m-1],g[2m]).
__device__ h2_t g_wtabh[NP * WSTR];

__global__ void init_wtab_kernel() {
    int p = threadIdx.x;
    if (p >= NP) return;
    const double stepd = 50.0 / 31.0;
    double coc = (p < 31) ? (double)p * stepd : 50.0;   // numpy linspace semantics
    float g[KC + 1];
    for (int i = 0; i <= KC; ++i) g[i] = 0.f;
    if (coc < 0.5) {
        g[KC / 2] = 1.f;  // identity plane
    } else {
        double sigma = coc / 2.355;
        int k = (int)(2.0 * coc + 1.0);   // trunc, matches python int()
        if ((k & 1) == 0) k += 1;
        if (k > KC) k = KC;
        int h = k / 2;
        float denom = (float)(2.0 * sigma * sigma);
        float tmp[KC];
        float s = 0.f;
        for (int t = 0; t < k; ++t) {
            float cd = (float)(t - h);
            float v = expf(-(cd * cd) / denom);
            tmp[t] = v;
            s += v;
        }
        for (int t = 0; t < k; ++t) g[(KC / 2) - h + t] = tmp[t] / s;
    }
    for (int m = 0; m < 16; ++m) {
        h2_t a, b;
        a.x = (_Float16)g[2 * m];
        a.y = (_Float16)g[2 * m + 1];                       // g[31]==0
        b.x = (_Float16)((2 * m - 1 >= 0) ? g[2 * m - 1] : 0.f);
        b.y = (_Float16)g[2 * m];
        g_wtabh[p * WSTR + m] = a;
        g_wtabh[p * WSTR + 16 + m] = b;
    }
    h2_t z; z.x = (_Float16)0.f; z.y = (_Float16)0.f;
    for (int m = 32; m < WSTR; ++m) g_wtabh[p * WSTR + m] = z;  // pad hygiene
}

__device__ __forceinline__ double plane_of(int i) {
    const double stepd = 50.0 / 31.0;
    return (i < 31) ? (double)i * stepd : 50.0;
}

__launch_bounds__(256, 4)
__global__ void defocus_kernel(const float* __restrict__ img,
                               const float* __restrict__ coc,
                               float* __restrict__ out) {
    const int tx = threadIdx.x;            // 0..7
    const int ty = threadIdx.y;            // 0..31
    const int tid = ty * 8 + tx;
    const int tilex = blockIdx.x * TXO;
    const int tiley = blockIdx.y * TYO;
    const int b = blockIdx.z;

    __shared__ __align__(16) h2_t wtab[NP * WSTR];
    __shared__ __align__(16) h2_t tile[TROWS * TWORDS];

    for (int f = tid; f < NP * WSTR; f += 256) wtab[f] = g_wtabh[f];

    const int yo = tiley + ty;
    const int xo = tilex + tx * 4;

    // per-pixel bin index, exact double-precision boundary semantics
    const float4 cv = *(const float4*)&coc[((size_t)b * HH + yo) * WW + xo];
    const float cocf[4] = {cv.x, cv.y, cv.z, cv.w};
    int idx[4];
    #pragma unroll
    for (int j = 0; j < 4; ++j) {
        const double stepd = 50.0 / 31.0;
        double cd = (double)cocf[j];
        int i0 = (int)floor(cd / stepd + 0.5);
        i0 = min(max(i0, 0), 31);
        if (i0 > 0 && cd <= 0.5 * (plane_of(i0 - 1) + plane_of(i0))) {
            i0 -= 1;
        } else if (i0 < 31 && cd > 0.5 * (plane_of(i0) + plane_of(i0 + 1))) {
            i0 += 1;
        }
        idx[j] = i0;
    }

    __syncthreads();  // wtab staged

    // gather this thread's 4 weight rows into registers (one-time random-indexed reads)
    // even local col (j=0,2): phase A; odd (j=1,3): phase B (pre-shifted by one tap)
    h2_t wj[4][16];
    #pragma unroll
    for (int j = 0; j < 4; ++j) {
        const h2_t* wp = &wtab[idx[j] * WSTR + (j & 1) * 16];
        #pragma unroll
        for (int m = 0; m < 4; ++m) {
            h8_t v = *(const h8_t*)(wp + 4 * m);   // 16B aligned: WSTR%4==0
            #pragma unroll
            for (int q = 0; q < 4; ++q) {
                h2_t t; t.x = v[2 * q]; t.y = v[2 * q + 1];
                wj[j][4 * m + q] = t;
            }
        }
    }

    for (int c = 0; c < CC; ++c) {
        __syncthreads();  // previous channel's readers done
        const float* src = img + (size_t)(b * CC + c) * HH * WW;
        for (int f = tid; f < TROWS * TWORDS; f += 256) {
            int r = f / TWORDS;
            int w = f - r * TWORDS;
            int gy = tiley - 15 + r;
            int gx = tilex - 15 + 2 * w;
            float v0 = 0.f, v1 = 0.f;
            if ((unsigned)gy < (unsigned)HH) {
                if ((unsigned)gx < (unsigned)WW) v0 = src[gy * WW + gx];
                if ((unsigned)(gx + 1) < (unsigned)WW) v1 = src[gy * WW + gx + 1];
            }
            h2_t pv; pv.x = (_Float16)v0; pv.y = (_Float16)v1;
            tile[f] = pv;
        }
        __syncthreads();

        float acc0 = 0.f, acc1 = 0.f, acc2 = 0.f, acc3 = 0.f;
        const h2_t* rowbase = &tile[ty * TWORDS + 2 * tx];
        #pragma unroll
        for (int dy = 0; dy < KC; ++dy) {
            const h2_t* rp = rowbase + dy * TWORDS;
            h2_t rw[18];
            #pragma unroll
            for (int m = 0; m < 9; ++m) {
                h4_t q = *(const h4_t*)(rp + 2 * m);   // ds_read_b64, conflict-free layout
                h2_t lo; lo.x = q[0]; lo.y = q[1];
                h2_t hi; hi.x = q[2]; hi.y = q[3];
                rw[2 * m]     = lo;
                rw[2 * m + 1] = hi;
            }
            float rs0 = 0.f, rs1 = 0.f, rs2 = 0.f, rs3 = 0.f;
            #pragma unroll
            for (int m = 0; m < 16; ++m) {
                rs0 = __builtin_amdgcn_fdot2(wj[0][m], rw[m],     rs0, false);
                rs1 = __builtin_amdgcn_fdot2(wj[1][m], rw[m],     rs1, false);
                rs2 = __builtin_amdgcn_fdot2(wj[2][m], rw[m + 1], rs2, false);
                rs3 = __builtin_amdgcn_fdot2(wj[3][m], rw[m + 1], rs3, false);
            }
            // column taps g[dy] from the same registers (dy unrolled -> static indices)
            float cw0, cw1, cw2, cw3;
            if ((dy & 1) == 0) {
                cw0 = (float)wj[0][dy >> 1].x;           // A: lo = g[dy]
                cw2 = (float)wj[2][dy >> 1].x;
                cw1 = (float)wj[1][dy >> 1].y;           // B: hi = g[dy]
                cw3 = (float)wj[3][dy >> 1].y;
            } else {
                cw0 = (float)wj[0][dy >> 1].y;           // A: hi = g[dy]
                cw2 = (float)wj[2][dy >> 1].y;
                cw1 = (float)wj[1][(dy + 1) >> 1].x;     // B: lo of next word = g[dy]
                cw3 = (float)wj[3][(dy + 1) >> 1].x;
            }
            acc0 += cw0 * rs0;
            acc1 += cw1 * rs1;
            acc2 += cw2 * rs2;
            acc3 += cw3 * rs3;
        }

        *(float4*)&out[((size_t)(b * CC + c) * HH + yo) * WW + xo] =
            make_float4(acc0, acc1, acc2, acc3);
    }
}

extern "C" void kernel_launch(void* const* d_in, const int* in_sizes, int n_in,
                              void* d_out, int out_size, void* d_ws, size_t ws_size,
                              hipStream_t stream) {
    const float* sharp = (const float*)d_in[0];
    const float* cocm  = (const float*)d_in[1];
    float* out = (float*)d_out;

    init_wtab_kernel<<<1, 64, 0, stream>>>();
    dim3 grid(WW / TXO, HH / TYO, BB);
    dim3 block(8, 32, 1);
    defocus_kernel<<<grid, block, 0, stream>>>(sharp, cocm, out);
}

// Round 3
// 146.979 us; speedup vs baseline: 2.1323x; 2.1006x over previous
//
#include <hip/hip_runtime.h>
#include <math.h>

typedef _Float16 h2_t __attribute__((ext_vector_type(2)));
typedef _Float16 h4_t __attribute__((ext_vector_type(4)));
typedef _Float16 h8_t __attribute__((ext_vector_type(8)));

#define NP 32
#define KC 31
#define HH 512
#define WW 512
#define BB 4
#define CC 3

#define TXO 32
#define TYO 32
#define TROWS 62      // 32 outputs + 15 + 15 halo
#define TWORDS 48     // half2-words per tile row (96 halves, 62 used, stride%32==16)
#define WSTR 36       // weight table plane stride in half2-words

// Packed per-plane 1D Gaussian taps, phase A = (g[2m],g[2m+1]), phase B = (g[2m-1],g[2m]).
__device__ h2_t g_wtabh[NP * WSTR];

// 32 planes x 32 lanes: one padded tap per lane, shfl-reduce the normalizer,
// shuffle-pack both phases. Replaces the former serial 1-wave init (~70 us -> ~2 us).
__global__ void init_wtab_kernel() {
    const int tid = threadIdx.x;          // 0..1023
    const int p = tid >> 5;               // plane
    const int t = tid & 31;               // padded tap position 0..31 (g[31]==0)
    const double stepd = 50.0 / 31.0;
    double coc = (p < 31) ? (double)p * stepd : 50.0;   // numpy linspace semantics
    float gt;
    if (coc < 0.5) {
        gt = (t == 15) ? 1.f : 0.f;       // identity plane (plane 0 only)
    } else {
        double sigma = coc / 2.355;
        int k = (int)(2.0 * coc + 1.0);   // trunc, matches python int()
        if ((k & 1) == 0) k += 1;
        if (k > KC) k = KC;
        int h = k / 2;
        int d = t - 15;
        float denom = (float)(2.0 * sigma * sigma);
        float v = (d >= -h && d <= h && t < KC) ? expf(-(float)(d * d) / denom) : 0.f;
        float s = v;
        #pragma unroll
        for (int off = 1; off < 32; off <<= 1) s += __shfl_xor(s, off, 32);
        gt = v / s;
    }
    // pack: lanes 0..15 build phase-A word m=t: (g[2m], g[2m+1])
    //       lanes 16..31 build phase-B word m=t-16: (g[2m-1], g[2m])
    const int m = t & 15;
    const int s0 = (t < 16) ? (2 * m) : ((2 * m - 1 < 0) ? 0 : 2 * m - 1);
    const int s1 = (t < 16) ? (2 * m + 1) : (2 * m);
    float w0 = __shfl(gt, s0, 32);
    float w1 = __shfl(gt, s1, 32);
    if (t >= 16 && (2 * m - 1) < 0) w0 = 0.f;   // g[-1] = 0
    h2_t w; w.x = (_Float16)w0; w.y = (_Float16)w1;
    g_wtabh[p * WSTR + t] = w;
    if (t < WSTR - 32) {                  // zero the 4 pad words
        h2_t z; z.x = (_Float16)0.f; z.y = (_Float16)0.f;
        g_wtabh[p * WSTR + 32 + t] = z;
    }
}

__device__ __forceinline__ double plane_of(int i) {
    const double stepd = 50.0 / 31.0;
    return (i < 31) ? (double)i * stepd : 50.0;
}

// (256,2): 256-VGPR allocator cap. (256,4)'s 128 cap made the compiler spill
// wj[4][16] to scratch (measured: VGPR=64, WRITE_SIZE 252 MB vs 12.6 MB output).
__launch_bounds__(256, 2)
__global__ void defocus_kernel(const float* __restrict__ img,
                               const float* __restrict__ coc,
                               float* __restrict__ out) {
    const int tx = threadIdx.x;            // 0..7
    const int ty = threadIdx.y;            // 0..31
    const int tid = ty * 8 + tx;
    const int tilex = blockIdx.x * TXO;
    const int tiley = blockIdx.y * TYO;
    const int b = blockIdx.z;

    __shared__ __align__(16) h2_t wtab[NP * WSTR];
    __shared__ __align__(16) h2_t tile[TROWS * TWORDS];

    for (int f = tid; f < NP * WSTR; f += 256) wtab[f] = g_wtabh[f];

    const int yo = tiley + ty;
    const int xo = tilex + tx * 4;

    // per-pixel bin index, exact double-precision boundary semantics
    const float4 cv = *(const float4*)&coc[((size_t)b * HH + yo) * WW + xo];
    const float cocf[4] = {cv.x, cv.y, cv.z, cv.w};
    int idx[4];
    #pragma unroll
    for (int j = 0; j < 4; ++j) {
        const double stepd = 50.0 / 31.0;
        double cd = (double)cocf[j];
        int i0 = (int)floor(cd / stepd + 0.5);
        i0 = min(max(i0, 0), 31);
        if (i0 > 0 && cd <= 0.5 * (plane_of(i0 - 1) + plane_of(i0))) {
            i0 -= 1;
        } else if (i0 < 31 && cd > 0.5 * (plane_of(i0) + plane_of(i0 + 1))) {
            i0 += 1;
        }
        idx[j] = i0;
    }

    __syncthreads();  // wtab staged

    // gather this thread's 4 weight rows into registers (one-time random-indexed reads)
    // even local col (j=0,2): phase A; odd (j=1,3): phase B (pre-shifted by one tap)
    h2_t wj[4][16];
    #pragma unroll
    for (int j = 0; j < 4; ++j) {
        const h2_t* wp = &wtab[idx[j] * WSTR + (j & 1) * 16];
        #pragma unroll
        for (int m = 0; m < 4; ++m) {
            h8_t v = *(const h8_t*)(wp + 4 * m);   // 16B aligned: WSTR%4==0
            #pragma unroll
            for (int q = 0; q < 4; ++q) {
                h2_t t; t.x = v[2 * q]; t.y = v[2 * q + 1];
                wj[j][4 * m + q] = t;
            }
        }
    }

    for (int c = 0; c < CC; ++c) {
        __syncthreads();  // previous channel's readers done
        const float* src = img + (size_t)(b * CC + c) * HH * WW;
        for (int f = tid; f < TROWS * TWORDS; f += 256) {
            int r = f / TWORDS;
            int w = f - r * TWORDS;
            int gy = tiley - 15 + r;
            int gx = tilex - 15 + 2 * w;
            float v0 = 0.f, v1 = 0.f;
            if ((unsigned)gy < (unsigned)HH) {
                if ((unsigned)gx < (unsigned)WW) v0 = src[gy * WW + gx];
                if ((unsigned)(gx + 1) < (unsigned)WW) v1 = src[gy * WW + gx + 1];
            }
            h2_t pv; pv.x = (_Float16)v0; pv.y = (_Float16)v1;
            tile[f] = pv;
        }
        __syncthreads();

        float acc0 = 0.f, acc1 = 0.f, acc2 = 0.f, acc3 = 0.f;
        const h2_t* rowbase = &tile[ty * TWORDS + 2 * tx];
        #pragma unroll
        for (int dy = 0; dy < KC; ++dy) {
            const h2_t* rp = rowbase + dy * TWORDS;
            h2_t rw[18];
            #pragma unroll
            for (int m = 0; m < 9; ++m) {
                h4_t q = *(const h4_t*)(rp + 2 * m);   // ds_read_b64, conflict-free layout
                h2_t lo; lo.x = q[0]; lo.y = q[1];
                h2_t hi; hi.x = q[2]; hi.y = q[3];
                rw[2 * m]     = lo;
                rw[2 * m + 1] = hi;
            }
            float rs0 = 0.f, rs1 = 0.f, rs2 = 0.f, rs3 = 0.f;
            #pragma unroll
            for (int m = 0; m < 16; ++m) {
                rs0 = __builtin_amdgcn_fdot2(wj[0][m], rw[m],     rs0, false);
                rs1 = __builtin_amdgcn_fdot2(wj[1][m], rw[m],     rs1, false);
                rs2 = __builtin_amdgcn_fdot2(wj[2][m], rw[m + 1], rs2, false);
                rs3 = __builtin_amdgcn_fdot2(wj[3][m], rw[m + 1], rs3, false);
            }
            // column taps g[dy] from the same registers (dy unrolled -> static indices)
            float cw0, cw1, cw2, cw3;
            if ((dy & 1) == 0) {
                cw0 = (float)wj[0][dy >> 1].x;           // A: lo = g[dy]
                cw2 = (float)wj[2][dy >> 1].x;
                cw1 = (float)wj[1][dy >> 1].y;           // B: hi = g[dy]
                cw3 = (float)wj[3][dy >> 1].y;
            } else {
                cw0 = (float)wj[0][dy >> 1].y;           // A: hi = g[dy]
                cw2 = (float)wj[2][dy >> 1].y;
                cw1 = (float)wj[1][(dy + 1) >> 1].x;     // B: lo of next word = g[dy]
                cw3 = (float)wj[3][(dy + 1) >> 1].x;
            }
            acc0 += cw0 * rs0;
            acc1 += cw1 * rs1;
            acc2 += cw2 * rs2;
            acc3 += cw3 * rs3;
        }

        *(float4*)&out[((size_t)(b * CC + c) * HH + yo) * WW + xo] =
            make_float4(acc0, acc1, acc2, acc3);
    }
}

extern "C" void kernel_launch(void* const* d_in, const int* in_sizes, int n_in,
                              void* d_out, int out_size, void* d_ws, size_t ws_size,
                              hipStream_t stream) {
    const float* sharp = (const float*)d_in[0];
    const float* cocm  = (const float*)d_in[1];
    float* out = (float*)d_out;

    init_wtab_kernel<<<1, 1024, 0, stream>>>();
    dim3 grid(WW / TXO, HH / TYO, BB);
    dim3 block(8, 32, 1);
    defocus_kernel<<<grid, block, 0, stream>>>(sharp, cocm, out);
}